// Round 13
// baseline (243.371 us; speedup 1.0000x reference)
//
#include <hip/hip_runtime.h>
#include <hip/hip_bf16.h>

typedef __attribute__((ext_vector_type(8))) short bf16x8;
typedef __attribute__((ext_vector_type(4))) float f32x4;

#if defined(__has_builtin)
#if __has_builtin(__builtin_amdgcn_global_load_lds)
#define USE_GLOAD_LDS 1
#endif
#endif

__device__ __forceinline__ void gload_lds16(const void* g, void* ldsbase) {
#ifdef USE_GLOAD_LDS
    __builtin_amdgcn_global_load_lds(
        (__attribute__((address_space(1))) void*)(g),
        (__attribute__((address_space(3))) void*)(ldsbase), 16, 0, 0);
#endif
}

__device__ __forceinline__ unsigned short f2bf(float f) {
    __hip_bfloat16 h = __float2bfloat16(f);
    return *reinterpret_cast<unsigned short*>(&h);
}

// ============ K1 early: pool (16384) + g_w transpose (512) + w_w cvt (256) + prepbias (32)
__global__ __launch_bounds__(256) void early_kernel(
        const float* __restrict__ x, float* __restrict__ xbar,
        const float* __restrict__ gw, const float* __restrict__ ww,
        __hip_bfloat16* __restrict__ gwt, __hip_bfloat16* __restrict__ wwb,
        const float* __restrict__ gb, const float* __restrict__ wb,
        const float* __restrict__ gamma, const float* __restrict__ beta,
        const float* __restrict__ mean, const float* __restrict__ var,
        float* __restrict__ inv, float* __restrict__ shift) {
    __shared__ float tile[32][33];
    int bid = blockIdx.x;
    int tid = threadIdx.x;
    if (bid < 16384) {
        int row = bid * 16 + (tid >> 4);
        int j = tid & 15;
        const float4* p = (const float4*)(x + (size_t)row * 128);
        float4 a = p[j * 2], b2 = p[j * 2 + 1];
        float s = a.x + a.y + a.z + a.w + b2.x + b2.y + b2.z + b2.w;
        s += __shfl_xor(s, 1); s += __shfl_xor(s, 2);
        s += __shfl_xor(s, 4); s += __shfl_xor(s, 8);
        if (j == 0) xbar[row] = s * (1.0f / 128.0f);
    } else if (bid < 16896) {
        int b2 = bid - 16384;
        int icb = b2 >> 5, cb = b2 & 31;
        int r = tid >> 5, c = tid & 31;
        #pragma unroll
        for (int i = 0; i < 4; i++)
            tile[r + i * 8][c] = gw[(size_t)(icb * 32 + r + i * 8) * 1024 + cb * 32 + c];
        __syncthreads();
        #pragma unroll
        for (int i = 0; i < 4; i++) {
            int cin = cb * 32 + r + i * 8;
            gwt[(size_t)cin * 512 + icb * 32 + c] = __float2bfloat16(tile[c][r + i * 8]);
        }
    } else if (bid < 17152) {
        int b2 = bid - 16896;
        size_t base = (size_t)b2 * 2048 + (size_t)tid * 8;
        const float4* src = (const float4*)(ww + base);
        float4 v0 = src[0], v1 = src[1];
        __hip_bfloat16 tmp[8];
        tmp[0] = __float2bfloat16(v0.x); tmp[1] = __float2bfloat16(v0.y);
        tmp[2] = __float2bfloat16(v0.z); tmp[3] = __float2bfloat16(v0.w);
        tmp[4] = __float2bfloat16(v1.x); tmp[5] = __float2bfloat16(v1.y);
        tmp[6] = __float2bfloat16(v1.z); tmp[7] = __float2bfloat16(v1.w);
        *(bf16x8*)(wwb + base) = *(const bf16x8*)tmp;
    } else {
        int b2 = bid - 17152;
        int wv = tid >> 6, l = tid & 63;
        int c = b2 * 32 + wv * 8 + (l >> 3);
        int j = l & 7;
        const float* wr = ww + (size_t)c * 512;
        float acc = 0.0f;
        #pragma unroll 8
        for (int k = j; k < 512; k += 8) acc += wr[k] * gb[k];
        acc += __shfl_xor(acc, 1); acc += __shfl_xor(acc, 2); acc += __shfl_xor(acc, 4);
        if (j == 0) {
            float cb2 = wb[c] + acc;
            float iv = gamma[c] * rsqrtf(var[c] + 1e-5f);
            inv[c] = iv;
            shift[c] = cb2 * iv + beta[c] - mean[c] * iv;
        }
    }
}

// ============ K2 stage2: thetaphi (128 blocks x 8 batches, L2 weight reuse) + prepM (64)
__global__ __launch_bounds__(256) void stage2_kernel(
        const float* __restrict__ xbar,
        const float* __restrict__ tw, const float* __restrict__ tb,
        const float* __restrict__ pw, const float* __restrict__ pb,
        float* __restrict__ theta, float* __restrict__ phi,
        const __hip_bfloat16* __restrict__ wwb,
        const __hip_bfloat16* __restrict__ gwt,
        __hip_bfloat16* __restrict__ M) {
    __shared__ __align__(16) char smem[33024];
    int bid = blockIdx.x;
    int tid = threadIdx.x;
    if (bid < 128) {
        // theta/phi: [b][ic][t] = W @ xbar[b][:][t] + bias. Block = (which, icc, bgroup of 8).
        // Weight rows re-read per b from L2 (both matrices = 4 MB, L2-resident).
        float* xs = (float*)smem;
        int which = bid & 1;
        int icc = (bid >> 1) & 15;
        int bg = bid >> 5;                         // 0..3
        const float* w = which ? pw : tw;
        const float* bias = which ? pb : tb;
        float* out = which ? phi : theta;
        int icl = tid >> 3, t = tid & 7;
        int ic = icc * 32 + icl;
        const float* wr = w + (size_t)ic * 1024;
        float bi = bias[ic];
        for (int bb = 0; bb < 8; ++bb) {
            int b = bg * 8 + bb;
            const float* xbb = xbar + b * 8192;
            if (bb) __syncthreads();               // xs safe to overwrite
            #pragma unroll
            for (int k = 0; k < 8; ++k) {
                int f4 = tid + k * 256;
                float4 v = *(const float4*)(xbb + (size_t)f4 * 4);
                int c = f4 >> 1;
                int t0 = (f4 & 1) * 4;
                xs[(t0 + 0) * 1028 + c] = v.x;
                xs[(t0 + 1) * 1028 + c] = v.y;
                xs[(t0 + 2) * 1028 + c] = v.z;
                xs[(t0 + 3) * 1028 + c] = v.w;
            }
            __syncthreads();
            const float* xr = xs + t * 1028;
            float a0 = 0.0f, a1 = 0.0f;
            #pragma unroll 4
            for (int k = 0; k < 1024; k += 8) {
                float4 wv0 = *(const float4*)(wr + k);
                float4 wv1 = *(const float4*)(wr + k + 4);
                float4 xv0 = *(const float4*)(xr + k);
                float4 xv1 = *(const float4*)(xr + k + 4);
                a0 = fmaf(wv0.x, xv0.x, a0); a0 = fmaf(wv0.y, xv0.y, a0);
                a0 = fmaf(wv0.z, xv0.z, a0); a0 = fmaf(wv0.w, xv0.w, a0);
                a1 = fmaf(wv1.x, xv1.x, a1); a1 = fmaf(wv1.y, xv1.y, a1);
                a1 = fmaf(wv1.z, xv1.z, a1); a1 = fmaf(wv1.w, xv1.w, a1);
            }
            out[((size_t)b * 512 + ic) * 8 + t] = a0 + a1 + bi;
        }
    } else {
        __hip_bfloat16* As = (__hip_bfloat16*)smem;
        __hip_bfloat16* Bs = (__hip_bfloat16*)(smem + 8192);
        int b2 = bid - 128;
        int mb = b2 >> 3, nb = b2 & 7;
        int c0 = mb * 128, n0 = nb * 128;
        int w = tid >> 6, l = tid & 63;
        int wr = w >> 1, wc = w & 1;
        const __hip_bfloat16* Ab = wwb + (size_t)c0 * 512;
        const __hip_bfloat16* Bb = gwt + (size_t)n0 * 512;
        int arow = tid >> 2, akq = tid & 3;
        f32x4 acc[4][4] = {};
        for (int kk = 0; kk < 16; ++kk) {
            int k0 = kk * 32;
#ifdef USE_GLOAD_LDS
            gload_lds16(Ab + (size_t)arow * 512 + k0 + akq * 8,        (char*)As + w * 1024);
            gload_lds16(Ab + (size_t)(arow + 64) * 512 + k0 + akq * 8, (char*)As + 4096 + w * 1024);
            gload_lds16(Bb + (size_t)arow * 512 + k0 + akq * 8,        (char*)Bs + w * 1024);
            gload_lds16(Bb + (size_t)(arow + 64) * 512 + k0 + akq * 8, (char*)Bs + 4096 + w * 1024);
#else
            *(bf16x8*)((char*)As + (size_t)tid * 16)        = *(const bf16x8*)(Ab + (size_t)arow * 512 + k0 + akq * 8);
            *(bf16x8*)((char*)As + 4096 + (size_t)tid * 16) = *(const bf16x8*)(Ab + (size_t)(arow + 64) * 512 + k0 + akq * 8);
            *(bf16x8*)((char*)Bs + (size_t)tid * 16)        = *(const bf16x8*)(Bb + (size_t)arow * 512 + k0 + akq * 8);
            *(bf16x8*)((char*)Bs + 4096 + (size_t)tid * 16) = *(const bf16x8*)(Bb + (size_t)(arow + 64) * 512 + k0 + akq * 8);
#endif
            __syncthreads();
            const __hip_bfloat16* Ap = As + ((size_t)(wr * 64 + (l & 15)) * 32) + (l >> 4) * 8;
            const __hip_bfloat16* Bp = Bs + ((size_t)(wc * 64 + (l & 15)) * 32) + (l >> 4) * 8;
            bf16x8 af[4], bfr[4];
            #pragma unroll
            for (int m = 0; m < 4; m++) af[m] = *(const bf16x8*)(Ap + m * 16 * 32);
            #pragma unroll
            for (int n = 0; n < 4; n++) bfr[n] = *(const bf16x8*)(Bp + n * 16 * 32);
            #pragma unroll
            for (int m = 0; m < 4; m++)
                #pragma unroll
                for (int n = 0; n < 4; n++)
                    acc[m][n] = __builtin_amdgcn_mfma_f32_16x16x32_bf16(af[m], bfr[n], acc[m][n], 0, 0, 0);
            __syncthreads();
        }
        int col = l & 15, rg = l >> 4;
        #pragma unroll
        for (int m = 0; m < 4; m++)
            #pragma unroll
            for (int j = 0; j < 4; j++) {
                int gc = c0 + wr * 64 + m * 16 + rg * 4 + j;
                #pragma unroll
                for (int n = 0; n < 4; n++)
                    M[(size_t)gc * 1024 + n0 + wc * 64 + n * 16 + col] = __float2bfloat16(acc[m][n][j]);
            }
    }
}

// ------------------------------------------------------- attn[b][t][s] = softmax_s(theta.phi)
__global__ __launch_bounds__(64) void attn_kernel(const float* __restrict__ theta,
                                                  const float* __restrict__ phi,
                                                  float* __restrict__ attn) {
    __shared__ float th[4096], ph[4096];
    int b = blockIdx.x, lane = threadIdx.x;
    for (int i = lane; i < 4096; i += 64) {
        th[i] = theta[(size_t)b * 4096 + i];
        ph[i] = phi[(size_t)b * 4096 + i];
    }
    __syncthreads();
    int t = lane >> 3, s = lane & 7;
    float f = 0.0f;
    #pragma unroll 8
    for (int ic = 0; ic < 512; ic++) f += th[ic * 8 + t] * ph[ic * 8 + s];
    float m = f;
    m = fmaxf(m, __shfl_xor(m, 1));
    m = fmaxf(m, __shfl_xor(m, 2));
    m = fmaxf(m, __shfl_xor(m, 4));
    float e = __expf(f - m);
    float sum = e;
    sum += __shfl_xor(sum, 1); sum += __shfl_xor(sum, 2); sum += __shfl_xor(sum, 4);
    attn[b * 64 + lane] = e / sum;
}

// ===== mix v2 (R10, proven): full-row coalesced reads. block = (b, 32-ch chunk), grid 1024 =====
// xmt[b][t*128+hw][c] = sum_s attn[b][t][s] * x[b][c][s][hw]
__global__ __launch_bounds__(256) void mix_kernel(const float* __restrict__ x,
                                                  const float* __restrict__ attn,
                                                  __hip_bfloat16* __restrict__ xmt) {
    int orig = blockIdx.x;
    int wg = (orig & 7) * 128 + (orig >> 3);      // XCD chunk (1024 % 8 == 0)
    int b = wg >> 5;
    int c0 = (wg & 31) * 32;
    __shared__ float at[64];
    __shared__ __align__(8) unsigned short xls[32 * 1028];
    int tid = threadIdx.x;
    if (tid < 64) at[tid] = attn[b * 64 + tid];
    const float* xb = x + ((size_t)b << 20) + (size_t)c0 * 1024;
    #pragma unroll
    for (int k = 0; k < 32; ++k) {
        int f4 = tid + k * 256;                   // 0..8191
        float4 v = *(const float4*)(xb + (size_t)f4 * 4);
        int ci = f4 >> 8;
        int rem = (f4 & 255) * 4;
        unsigned short h[4];
        h[0] = f2bf(v.x); h[1] = f2bf(v.y); h[2] = f2bf(v.z); h[3] = f2bf(v.w);
        *(ushort4*)(&xls[ci * 1028 + rem]) = *(const ushort4*)h;
    }
    __syncthreads();
    int ci = tid & 31, h2 = tid >> 5;
    const unsigned short* basep = &xls[ci * 1028];
    __hip_bfloat16* ob = xmt + ((size_t)b << 20) + c0 + ci;
    #pragma unroll
    for (int i = 0; i < 8; ++i) {
        int hw0 = (h2 + 8 * i) * 2;
        float o0[8] = {}, o1[8] = {};
        #pragma unroll
        for (int s = 0; s < 8; ++s) {
            unsigned int pr = *(const unsigned int*)(basep + s * 128 + hw0);
            float v0 = __uint_as_float(pr << 16);
            float v1 = __uint_as_float(pr & 0xffff0000u);
            #pragma unroll
            for (int t = 0; t < 8; ++t) {
                float a = at[t * 8 + s];
                o0[t] = fmaf(a, v0, o0[t]);
                o1[t] = fmaf(a, v1, o1[t]);
            }
        }
        #pragma unroll
        for (int t = 0; t < 8; ++t) {
            size_t nn = (size_t)(t * 128 + hw0) * 1024;
            ob[nn] = __float2bfloat16(o0[t]);
            ob[nn + 1024] = __float2bfloat16(o1[t]);
        }
    }
}

// ===== 256x128-tile / 8-wave GEMM, K32 dbuf + counted vmcnt(3), 2 blocks/CU (48 KB LDS) =====
// out[b][c][n] = inv[c] * sum_k M[c][k]*xmt[b][n][k] + shift[c] + x[b][c][n]
// NOTE: 2 blocks/CU is the register ceiling for this tile (64 acc + 64 VGPR = 128 = cap at
// 4 waves/SIMD); 3 blocks/CU would need <=85 regs -> spill (R6 lesson). Do not raise.
__global__ __launch_bounds__(512, 4) void gemm256x128_kernel(
        const __hip_bfloat16* __restrict__ Mw,    // [1024][1024]  (c, k)
        const __hip_bfloat16* __restrict__ xmt,   // [32][1024][1024] (n, k)
        const float* __restrict__ x,              // [32][1024][1024] (c, n)
        const float* __restrict__ inv, const float* __restrict__ shift,
        float* __restrict__ out) {
    __shared__ __align__(16) __hip_bfloat16 HBs[24576];        // 48 KiB = 2 x 24 KiB
    char* AH = (char*)HBs;
    const int BUFB = 24576;

    int orig = blockIdx.x;
    int bid = (orig & 7) * 128 + (orig >> 3);     // XCD chunk (1024 % 8 == 0)
    int b = bid >> 5;
    int mb = (bid >> 3) & 3;
    int nb = bid & 7;
    int c0 = mb * 256, n0 = nb * 128;

    int tid = threadIdx.x;
    int w = tid >> 6, l = tid & 63;
    int wr = w >> 1, wc = w & 1;                  // 4x2 waves; wave out = 64(M) x 64(N)

    int sgl = (((l & 3) - ((l >> 3) & 3)) & 3);
    const __hip_bfloat16* aS = Mw + (size_t)(c0 + w * 16 + (l >> 2)) * 1024 + sgl * 8;
    const __hip_bfloat16* bS = xmt + ((size_t)b << 20) + (size_t)(n0 + w * 16 + (l >> 2)) * 1024 + sgl * 8;
    int stBase = w * 1024;

    int rdSlot = ((l >> 4) + (((l & 15) >> 1) & 3)) & 3;
    int aRdBase = (wr * 64 + (l & 15)) * 64 + rdSlot * 16;          // A region: 16 KB
    int bRdBase = 16384 + (wc * 64 + (l & 15)) * 64 + rdSlot * 16;  // B region: 8 KB

    f32x4 acc[4][4] = {};

    #define ISSUE(q) do {                                                       \
        gload_lds16(aS,              AH + (q) * BUFB + stBase);                 \
        gload_lds16(aS + 128 * 1024, AH + (q) * BUFB + 8192 + stBase);          \
        gload_lds16(bS,              AH + (q) * BUFB + 16384 + stBase);         \
        aS += 32; bS += 32;                                                     \
    } while (0)

    #define V3 asm volatile("s_waitcnt vmcnt(3)" ::: "memory")
    #define V0 asm volatile("s_waitcnt vmcnt(0)" ::: "memory")
    #define SB0 __builtin_amdgcn_sched_barrier(0)
    #define BAR __builtin_amdgcn_s_barrier()
    #define LGKM0 asm volatile("s_waitcnt lgkmcnt(0)" ::: "memory")

    #define HSTEP(q, MODE) do {                                                 \
        const char* bp = AH + (q) * BUFB;                                       \
        bf16x8 af0 = *(const bf16x8*)(bp + aRdBase);                            \
        bf16x8 af1 = *(const bf16x8*)(bp + aRdBase + 1024);                     \
        bf16x8 af2 = *(const bf16x8*)(bp + aRdBase + 2048);                     \
        bf16x8 af3 = *(const bf16x8*)(bp + aRdBase + 3072);                     \
        bf16x8 bf0 = *(const bf16x8*)(bp + bRdBase);                            \
        bf16x8 bf1 = *(const bf16x8*)(bp + bRdBase + 1024);                     \
        bf16x8 bf2 = *(const bf16x8*)(bp + bRdBase + 2048);                     \
        bf16x8 bf3 = *(const bf16x8*)(bp + bRdBase + 3072);                     \
        LGKM0; SB0;                                                             \
        BAR;                                                                    \
        if ((MODE) == 0) ISSUE(q);                                              \
        SB0;                                                                    \
        __builtin_amdgcn_s_setprio(1);                                          \
        _Pragma("unroll")                                                       \
        for (int n = 0; n < 4; ++n) {                                           \
            bf16x8 bfn = (n == 0) ? bf0 : (n == 1) ? bf1 : (n == 2) ? bf2 : bf3;\
            acc[0][n] = __builtin_amdgcn_mfma_f32_16x16x32_bf16(af0, bfn, acc[0][n], 0, 0, 0); \
            acc[1][n] = __builtin_amdgcn_mfma_f32_16x16x32_bf16(af1, bfn, acc[1][n], 0, 0, 0); \
            acc[2][n] = __builtin_amdgcn_mfma_f32_16x16x32_bf16(af2, bfn, acc[2][n], 0, 0, 0); \
            acc[3][n] = __builtin_amdgcn_mfma_f32_16x16x32_bf16(af3, bfn, acc[3][n], 0, 0, 0); \
        }                                                                       \
        __builtin_amdgcn_s_setprio(0);                                          \
        SB0;                                                                    \
        if ((MODE) == 0) { V3; BAR; SB0; }                                      \
        else if ((MODE) == 1) { V0; BAR; SB0; }                                 \
    } while (0)

    ISSUE(0); ISSUE(1);
    V3; BAR; SB0;

    #pragma unroll 1
    for (int t = 0; t < 15; ++t) {
        HSTEP(0, 0);
        HSTEP(1, 0);
    }
    HSTEP(0, 1);
    HSTEP(1, 2);

    #undef ISSUE
    #undef HSTEP
    #undef V3
    #undef V0
    #undef SB0
    #undef BAR
    #undef LGKM0

    int col = l & 15, rg = l >> 4;
    const float* xb = x + ((size_t)b << 20);
    float* ob = out + ((size_t)b << 20);
    #pragma unroll
    for (int mi = 0; mi < 4; ++mi) {
        #pragma unroll
        for (int j = 0; j < 4; ++j) {
            int gc = c0 + wr * 64 + mi * 16 + rg * 4 + j;
            float iv = inv[gc], sh = shift[gc];
            size_t rowoff = (size_t)gc * 1024 + n0 + wc * 64 + col;
            #pragma unroll
            for (int n = 0; n < 4; ++n) {
                size_t idx = rowoff + n * 16;
                ob[idx] = acc[mi][n][j] * iv + sh + xb[idx];
            }
        }
    }
}

extern "C" void kernel_launch(void* const* d_in, const int* in_sizes, int n_in,
                              void* d_out, int out_size, void* d_ws, size_t ws_size,
                              hipStream_t stream) {
    const float* x    = (const float*)d_in[0];
    const float* g_w  = (const float*)d_in[1];
    const float* g_b  = (const float*)d_in[2];
    const float* th_w = (const float*)d_in[3];
    const float* th_b = (const float*)d_in[4];
    const float* ph_w = (const float*)d_in[5];
    const float* ph_b = (const float*)d_in[6];
    const float* w_w  = (const float*)d_in[7];
    const float* w_b  = (const float*)d_in[8];
    const float* gam  = (const float*)d_in[9];
    const float* bet  = (const float*)d_in[10];
    const float* mea  = (const float*)d_in[11];
    const float* var  = (const float*)d_in[12];
    float* out = (float*)d_out;
    char* ws = (char*)d_ws;

    __hip_bfloat16* xmt = (__hip_bfloat16*)ws;                    // 64 MiB (written by mix, late)
    __hip_bfloat16* Mw  = (__hip_bfloat16*)(ws + 67108864);       // 2 MiB
    float* xbar  = (float*)(ws + 69206016);                       // 1 MiB
    float* theta = (float*)(ws + 70254592);                       // 512 KiB
    float* phi   = (float*)(ws + 70778880);                       // 512 KiB
    float* attn  = (float*)(ws + 71303168);                       // 8 KiB
    float* inv   = (float*)(ws + 71311360);                       // 4 KiB
    float* shift = (float*)(ws + 71315456);                       // 4 KiB
    // gwt/wwb overlay the xmt region: consumed by stage2 (prepM) BEFORE mix writes xmt
    __hip_bfloat16* gwt = (__hip_bfloat16*)ws;                    // 1 MiB
    __hip_bfloat16* wwb = (__hip_bfloat16*)(ws + 1048576);        // 1 MiB

    hipLaunchKernelGGL(early_kernel, dim3(17184), dim3(256), 0, stream,
                       x, xbar, g_w, w_w, gwt, wwb,
                       g_b, w_b, gam, bet, mea, var, inv, shift);
    hipLaunchKernelGGL(stage2_kernel, dim3(192), dim3(256), 0, stream,
                       xbar, th_w, th_b, ph_w, ph_b, theta, phi, wwb, gwt, Mw);
    hipLaunchKernelGGL(attn_kernel, dim3(32), dim3(64), 0, stream, theta, phi, attn);
    hipLaunchKernelGGL(mix_kernel, dim3(1024), dim3(256), 0, stream, x, attn, xmt);
    hipLaunchKernelGGL(gemm256x128_kernel, dim3(1024), dim3(512), 0, stream,
                       Mw, xmt, x, inv, shift, out);
}

// Round 14
// 217.778 us; speedup vs baseline: 1.1175x; 1.1175x over previous
//
#include <hip/hip_runtime.h>
#include <hip/hip_bf16.h>

typedef __attribute__((ext_vector_type(8))) short bf16x8;
typedef __attribute__((ext_vector_type(4))) float f32x4;

#if defined(__has_builtin)
#if __has_builtin(__builtin_amdgcn_global_load_lds)
#define USE_GLOAD_LDS 1
#endif
#endif

__device__ __forceinline__ void gload_lds16(const void* g, void* ldsbase) {
#ifdef USE_GLOAD_LDS
    __builtin_amdgcn_global_load_lds(
        (__attribute__((address_space(1))) void*)(g),
        (__attribute__((address_space(3))) void*)(ldsbase), 16, 0, 0);
#endif
}

__device__ __forceinline__ unsigned short f2bf(float f) {
    __hip_bfloat16 h = __float2bfloat16(f);
    return *reinterpret_cast<unsigned short*>(&h);
}

// ============ K1 early: pool (16384) + g_w transpose (512) + w_w cvt (256) + prepbias (32)
__global__ __launch_bounds__(256) void early_kernel(
        const float* __restrict__ x, float* __restrict__ xbar,
        const float* __restrict__ gw, const float* __restrict__ ww,
        __hip_bfloat16* __restrict__ gwt, __hip_bfloat16* __restrict__ wwb,
        const float* __restrict__ gb, const float* __restrict__ wb,
        const float* __restrict__ gamma, const float* __restrict__ beta,
        const float* __restrict__ mean, const float* __restrict__ var,
        float* __restrict__ inv, float* __restrict__ shift) {
    __shared__ float tile[32][33];
    int bid = blockIdx.x;
    int tid = threadIdx.x;
    if (bid < 16384) {
        int row = bid * 16 + (tid >> 4);
        int j = tid & 15;
        const float4* p = (const float4*)(x + (size_t)row * 128);
        float4 a = p[j * 2], b2 = p[j * 2 + 1];
        float s = a.x + a.y + a.z + a.w + b2.x + b2.y + b2.z + b2.w;
        s += __shfl_xor(s, 1); s += __shfl_xor(s, 2);
        s += __shfl_xor(s, 4); s += __shfl_xor(s, 8);
        if (j == 0) xbar[row] = s * (1.0f / 128.0f);
    } else if (bid < 16896) {
        int b2 = bid - 16384;
        int icb = b2 >> 5, cb = b2 & 31;
        int r = tid >> 5, c = tid & 31;
        #pragma unroll
        for (int i = 0; i < 4; i++)
            tile[r + i * 8][c] = gw[(size_t)(icb * 32 + r + i * 8) * 1024 + cb * 32 + c];
        __syncthreads();
        #pragma unroll
        for (int i = 0; i < 4; i++) {
            int cin = cb * 32 + r + i * 8;
            gwt[(size_t)cin * 512 + icb * 32 + c] = __float2bfloat16(tile[c][r + i * 8]);
        }
    } else if (bid < 17152) {
        int b2 = bid - 16896;
        size_t base = (size_t)b2 * 2048 + (size_t)tid * 8;
        const float4* src = (const float4*)(ww + base);
        float4 v0 = src[0], v1 = src[1];
        __hip_bfloat16 tmp[8];
        tmp[0] = __float2bfloat16(v0.x); tmp[1] = __float2bfloat16(v0.y);
        tmp[2] = __float2bfloat16(v0.z); tmp[3] = __float2bfloat16(v0.w);
        tmp[4] = __float2bfloat16(v1.x); tmp[5] = __float2bfloat16(v1.y);
        tmp[6] = __float2bfloat16(v1.z); tmp[7] = __float2bfloat16(v1.w);
        *(bf16x8*)(wwb + base) = *(const bf16x8*)tmp;
    } else {
        int b2 = bid - 17152;
        int wv = tid >> 6, l = tid & 63;
        int c = b2 * 32 + wv * 8 + (l >> 3);
        int j = l & 7;
        const float* wr = ww + (size_t)c * 512;
        float acc = 0.0f;
        #pragma unroll 8
        for (int k = j; k < 512; k += 8) acc += wr[k] * gb[k];
        acc += __shfl_xor(acc, 1); acc += __shfl_xor(acc, 2); acc += __shfl_xor(acc, 4);
        if (j == 0) {
            float cb2 = wb[c] + acc;
            float iv = gamma[c] * rsqrtf(var[c] + 1e-5f);
            inv[c] = iv;
            shift[c] = cb2 * iv + beta[c] - mean[c] * iv;
        }
    }
}

// ============ K2 stage2: thetaphi (1024, LDS-transposed b128 reads) + prepM via MFMA (64)
__global__ __launch_bounds__(256) void stage2_kernel(
        const float* __restrict__ xbar,
        const float* __restrict__ tw, const float* __restrict__ tb,
        const float* __restrict__ pw, const float* __restrict__ pb,
        float* __restrict__ theta, float* __restrict__ phi,
        const __hip_bfloat16* __restrict__ wwb,
        const __hip_bfloat16* __restrict__ gwt,
        __hip_bfloat16* __restrict__ M) {
    __shared__ __align__(16) char smem[33024];
    int bid = blockIdx.x;
    int tid = threadIdx.x;
    if (bid < 1024) {
        float* xs = (float*)smem;
        int which = bid & 1;
        int icc = (bid >> 1) & 15;
        int b = bid >> 5;
        const float* w = which ? pw : tw;
        const float* bias = which ? pb : tb;
        float* out = which ? phi : theta;
        const float* xbb = xbar + b * 8192;
        #pragma unroll
        for (int k = 0; k < 8; ++k) {
            int f4 = tid + k * 256;
            float4 v = *(const float4*)(xbb + (size_t)f4 * 4);
            int c = f4 >> 1;
            int t0 = (f4 & 1) * 4;
            xs[(t0 + 0) * 1028 + c] = v.x;
            xs[(t0 + 1) * 1028 + c] = v.y;
            xs[(t0 + 2) * 1028 + c] = v.z;
            xs[(t0 + 3) * 1028 + c] = v.w;
        }
        __syncthreads();
        int icl = tid >> 3, t = tid & 7;
        int ic = icc * 32 + icl;
        const float* wr = w + (size_t)ic * 1024;
        const float* xr = xs + t * 1028;
        float a0 = 0.0f, a1 = 0.0f;
        #pragma unroll 4
        for (int k = 0; k < 1024; k += 8) {
            float4 wv0 = *(const float4*)(wr + k);
            float4 wv1 = *(const float4*)(wr + k + 4);
            float4 xv0 = *(const float4*)(xr + k);
            float4 xv1 = *(const float4*)(xr + k + 4);
            a0 = fmaf(wv0.x, xv0.x, a0); a0 = fmaf(wv0.y, xv0.y, a0);
            a0 = fmaf(wv0.z, xv0.z, a0); a0 = fmaf(wv0.w, xv0.w, a0);
            a1 = fmaf(wv1.x, xv1.x, a1); a1 = fmaf(wv1.y, xv1.y, a1);
            a1 = fmaf(wv1.z, xv1.z, a1); a1 = fmaf(wv1.w, xv1.w, a1);
        }
        out[((size_t)b * 512 + ic) * 8 + t] = a0 + a1 + bias[ic];
    } else {
        __hip_bfloat16* As = (__hip_bfloat16*)smem;
        __hip_bfloat16* Bs = (__hip_bfloat16*)(smem + 8192);
        int b2 = bid - 1024;
        int mb = b2 >> 3, nb = b2 & 7;
        int c0 = mb * 128, n0 = nb * 128;
        int w = tid >> 6, l = tid & 63;
        int wr = w >> 1, wc = w & 1;
        const __hip_bfloat16* Ab = wwb + (size_t)c0 * 512;
        const __hip_bfloat16* Bb = gwt + (size_t)n0 * 512;
        int arow = tid >> 2, akq = tid & 3;
        f32x4 acc[4][4] = {};
        for (int kk = 0; kk < 16; ++kk) {
            int k0 = kk * 32;
#ifdef USE_GLOAD_LDS
            gload_lds16(Ab + (size_t)arow * 512 + k0 + akq * 8,        (char*)As + w * 1024);
            gload_lds16(Ab + (size_t)(arow + 64) * 512 + k0 + akq * 8, (char*)As + 4096 + w * 1024);
            gload_lds16(Bb + (size_t)arow * 512 + k0 + akq * 8,        (char*)Bs + w * 1024);
            gload_lds16(Bb + (size_t)(arow + 64) * 512 + k0 + akq * 8, (char*)Bs + 4096 + w * 1024);
#else
            *(bf16x8*)((char*)As + (size_t)tid * 16)        = *(const bf16x8*)(Ab + (size_t)arow * 512 + k0 + akq * 8);
            *(bf16x8*)((char*)As + 4096 + (size_t)tid * 16) = *(const bf16x8*)(Ab + (size_t)(arow + 64) * 512 + k0 + akq * 8);
            *(bf16x8*)((char*)Bs + (size_t)tid * 16)        = *(const bf16x8*)(Bb + (size_t)arow * 512 + k0 + akq * 8);
            *(bf16x8*)((char*)Bs + 4096 + (size_t)tid * 16) = *(const bf16x8*)(Bb + (size_t)(arow + 64) * 512 + k0 + akq * 8);
#endif
            __syncthreads();
            const __hip_bfloat16* Ap = As + ((size_t)(wr * 64 + (l & 15)) * 32) + (l >> 4) * 8;
            const __hip_bfloat16* Bp = Bs + ((size_t)(wc * 64 + (l & 15)) * 32) + (l >> 4) * 8;
            bf16x8 af[4], bfr[4];
            #pragma unroll
            for (int m = 0; m < 4; m++) af[m] = *(const bf16x8*)(Ap + m * 16 * 32);
            #pragma unroll
            for (int n = 0; n < 4; n++) bfr[n] = *(const bf16x8*)(Bp + n * 16 * 32);
            #pragma unroll
            for (int m = 0; m < 4; m++)
                #pragma unroll
                for (int n = 0; n < 4; n++)
                    acc[m][n] = __builtin_amdgcn_mfma_f32_16x16x32_bf16(af[m], bfr[n], acc[m][n], 0, 0, 0);
            __syncthreads();
        }
        int col = l & 15, rg = l >> 4;
        #pragma unroll
        for (int m = 0; m < 4; m++)
            #pragma unroll
            for (int j = 0; j < 4; j++) {
                int gc = c0 + wr * 64 + m * 16 + rg * 4 + j;
                #pragma unroll
                for (int n = 0; n < 4; n++)
                    M[(size_t)gc * 1024 + n0 + wc * 64 + n * 16 + col] = __float2bfloat16(acc[m][n][j]);
            }
    }
}

// ------------------------------------------------------- attn[b][t][s] = softmax_s(theta.phi)
__global__ __launch_bounds__(64) void attn_kernel(const float* __restrict__ theta,
                                                  const float* __restrict__ phi,
                                                  float* __restrict__ attn) {
    __shared__ float th[4096], ph[4096];
    int b = blockIdx.x, lane = threadIdx.x;
    for (int i = lane; i < 4096; i += 64) {
        th[i] = theta[(size_t)b * 4096 + i];
        ph[i] = phi[(size_t)b * 4096 + i];
    }
    __syncthreads();
    int t = lane >> 3, s = lane & 7;
    float f = 0.0f;
    #pragma unroll 8
    for (int ic = 0; ic < 512; ic++) f += th[ic * 8 + t] * ph[ic * 8 + s];
    float m = f;
    m = fmaxf(m, __shfl_xor(m, 1));
    m = fmaxf(m, __shfl_xor(m, 2));
    m = fmaxf(m, __shfl_xor(m, 4));
    float e = __expf(f - m);
    float sum = e;
    sum += __shfl_xor(sum, 1); sum += __shfl_xor(sum, 2); sum += __shfl_xor(sum, 4);
    attn[b * 64 + lane] = e / sum;
}

// ===== mix v2 (R10, proven): full-row coalesced reads. block = (b, 32-ch chunk), grid 1024 =====
// xmt[b][t*128+hw][c] = sum_s attn[b][t][s] * x[b][c][s][hw]
__global__ __launch_bounds__(256) void mix_kernel(const float* __restrict__ x,
                                                  const float* __restrict__ attn,
                                                  __hip_bfloat16* __restrict__ xmt) {
    int orig = blockIdx.x;
    int wg = (orig & 7) * 128 + (orig >> 3);      // XCD chunk (1024 % 8 == 0)
    int b = wg >> 5;
    int c0 = (wg & 31) * 32;
    __shared__ float at[64];
    __shared__ __align__(8) unsigned short xls[32 * 1028];
    int tid = threadIdx.x;
    if (tid < 64) at[tid] = attn[b * 64 + tid];
    const float* xb = x + ((size_t)b << 20) + (size_t)c0 * 1024;
    #pragma unroll
    for (int k = 0; k < 32; ++k) {
        int f4 = tid + k * 256;                   // 0..8191
        float4 v = *(const float4*)(xb + (size_t)f4 * 4);
        int ci = f4 >> 8;
        int rem = (f4 & 255) * 4;
        unsigned short h[4];
        h[0] = f2bf(v.x); h[1] = f2bf(v.y); h[2] = f2bf(v.z); h[3] = f2bf(v.w);
        *(ushort4*)(&xls[ci * 1028 + rem]) = *(const ushort4*)h;
    }
    __syncthreads();
    int ci = tid & 31, h2 = tid >> 5;
    const unsigned short* basep = &xls[ci * 1028];
    __hip_bfloat16* ob = xmt + ((size_t)b << 20) + c0 + ci;
    #pragma unroll
    for (int i = 0; i < 8; ++i) {
        int hw0 = (h2 + 8 * i) * 2;
        float o0[8] = {}, o1[8] = {};
        #pragma unroll
        for (int s = 0; s < 8; ++s) {
            unsigned int pr = *(const unsigned int*)(basep + s * 128 + hw0);
            float v0 = __uint_as_float(pr << 16);
            float v1 = __uint_as_float(pr & 0xffff0000u);
            #pragma unroll
            for (int t = 0; t < 8; ++t) {
                float a = at[t * 8 + s];
                o0[t] = fmaf(a, v0, o0[t]);
                o1[t] = fmaf(a, v1, o1[t]);
            }
        }
        #pragma unroll
        for (int t = 0; t < 8; ++t) {
            size_t nn = (size_t)(t * 128 + hw0) * 1024;
            ob[nn] = __float2bfloat16(o0[t]);
            ob[nn + 1024] = __float2bfloat16(o1[t]);
        }
    }
}

// ===== 256x128-tile / 8-wave GEMM, K32 dbuf + counted vmcnt(3), 2 blocks/CU (48 KB LDS) =====
// out[b][c][n] = inv[c] * sum_k M[c][k]*xmt[b][n][k] + shift[c] + x[b][c][n]
// NOTE: 2 blocks/CU is the register ceiling for this tile (64 acc + 64 VGPR = 128 = cap at
// 4 waves/SIMD); 3 blocks/CU would need <=85 regs -> spill (R6 lesson). Do not raise.
__global__ __launch_bounds__(512, 4) void gemm256x128_kernel(
        const __hip_bfloat16* __restrict__ Mw,    // [1024][1024]  (c, k)
        const __hip_bfloat16* __restrict__ xmt,   // [32][1024][1024] (n, k)
        const float* __restrict__ x,              // [32][1024][1024] (c, n)
        const float* __restrict__ inv, const float* __restrict__ shift,
        float* __restrict__ out) {
    __shared__ __align__(16) __hip_bfloat16 HBs[24576];        // 48 KiB = 2 x 24 KiB
    char* AH = (char*)HBs;
    const int BUFB = 24576;

    int orig = blockIdx.x;
    int bid = (orig & 7) * 128 + (orig >> 3);     // XCD chunk (1024 % 8 == 0)
    int b = bid >> 5;
    int mb = (bid >> 3) & 3;
    int nb = bid & 7;
    int c0 = mb * 256, n0 = nb * 128;

    int tid = threadIdx.x;
    int w = tid >> 6, l = tid & 63;
    int wr = w >> 1, wc = w & 1;                  // 4x2 waves; wave out = 64(M) x 64(N)

    int sgl = (((l & 3) - ((l >> 3) & 3)) & 3);
    const __hip_bfloat16* aS = Mw + (size_t)(c0 + w * 16 + (l >> 2)) * 1024 + sgl * 8;
    const __hip_bfloat16* bS = xmt + ((size_t)b << 20) + (size_t)(n0 + w * 16 + (l >> 2)) * 1024 + sgl * 8;
    int stBase = w * 1024;

    int rdSlot = ((l >> 4) + (((l & 15) >> 1) & 3)) & 3;
    int aRdBase = (wr * 64 + (l & 15)) * 64 + rdSlot * 16;          // A region: 16 KB
    int bRdBase = 16384 + (wc * 64 + (l & 15)) * 64 + rdSlot * 16;  // B region: 8 KB

    f32x4 acc[4][4] = {};

    #define ISSUE(q) do {                                                       \
        gload_lds16(aS,              AH + (q) * BUFB + stBase);                 \
        gload_lds16(aS + 128 * 1024, AH + (q) * BUFB + 8192 + stBase);          \
        gload_lds16(bS,              AH + (q) * BUFB + 16384 + stBase);         \
        aS += 32; bS += 32;                                                     \
    } while (0)

    #define V3 asm volatile("s_waitcnt vmcnt(3)" ::: "memory")
    #define V0 asm volatile("s_waitcnt vmcnt(0)" ::: "memory")
    #define SB0 __builtin_amdgcn_sched_barrier(0)
    #define BAR __builtin_amdgcn_s_barrier()
    #define LGKM0 asm volatile("s_waitcnt lgkmcnt(0)" ::: "memory")

    #define HSTEP(q, MODE) do {                                                 \
        const char* bp = AH + (q) * BUFB;                                       \
        bf16x8 af0 = *(const bf16x8*)(bp + aRdBase);                            \
        bf16x8 af1 = *(const bf16x8*)(bp + aRdBase + 1024);                     \
        bf16x8 af2 = *(const bf16x8*)(bp + aRdBase + 2048);                     \
        bf16x8 af3 = *(const bf16x8*)(bp + aRdBase + 3072);                     \
        bf16x8 bf0 = *(const bf16x8*)(bp + bRdBase);                            \
        bf16x8 bf1 = *(const bf16x8*)(bp + bRdBase + 1024);                     \
        bf16x8 bf2 = *(const bf16x8*)(bp + bRdBase + 2048);                     \
        bf16x8 bf3 = *(const bf16x8*)(bp + bRdBase + 3072);                     \
        LGKM0; SB0;                                                             \
        BAR;                                                                    \
        if ((MODE) == 0) ISSUE(q);                                              \
        SB0;                                                                    \
        __builtin_amdgcn_s_setprio(1);                                          \
        _Pragma("unroll")                                                       \
        for (int n = 0; n < 4; ++n) {                                           \
            bf16x8 bfn = (n == 0) ? bf0 : (n == 1) ? bf1 : (n == 2) ? bf2 : bf3;\
            acc[0][n] = __builtin_amdgcn_mfma_f32_16x16x32_bf16(af0, bfn, acc[0][n], 0, 0, 0); \
            acc[1][n] = __builtin_amdgcn_mfma_f32_16x16x32_bf16(af1, bfn, acc[1][n], 0, 0, 0); \
            acc[2][n] = __builtin_amdgcn_mfma_f32_16x16x32_bf16(af2, bfn, acc[2][n], 0, 0, 0); \
            acc[3][n] = __builtin_amdgcn_mfma_f32_16x16x32_bf16(af3, bfn, acc[3][n], 0, 0, 0); \
        }                                                                       \
        __builtin_amdgcn_s_setprio(0);                                          \
        SB0;                                                                    \
        if ((MODE) == 0) { V3; BAR; SB0; }                                      \
        else if ((MODE) == 1) { V0; BAR; SB0; }                                 \
    } while (0)

    ISSUE(0); ISSUE(1);
    V3; BAR; SB0;

    #pragma unroll 1
    for (int t = 0; t < 15; ++t) {
        HSTEP(0, 0);
        HSTEP(1, 0);
    }
    HSTEP(0, 1);
    HSTEP(1, 2);

    #undef ISSUE
    #undef HSTEP
    #undef V3
    #undef V0
    #undef SB0
    #undef BAR
    #undef LGKM0

    int col = l & 15, rg = l >> 4;
    const float* xb = x + ((size_t)b << 20);
    float* ob = out + ((size_t)b << 20);
    #pragma unroll
    for (int mi = 0; mi < 4; ++mi) {
        #pragma unroll
        for (int j = 0; j < 4; ++j) {
            int gc = c0 + wr * 64 + mi * 16 + rg * 4 + j;
            float iv = inv[gc], sh = shift[gc];
            size_t rowoff = (size_t)gc * 1024 + n0 + wc * 64 + col;
            #pragma unroll
            for (int n = 0; n < 4; ++n) {
                size_t idx = rowoff + n * 16;
                ob[idx] = acc[mi][n][j] * iv + sh + xb[idx];
            }
        }
    }
}

extern "C" void kernel_launch(void* const* d_in, const int* in_sizes, int n_in,
                              void* d_out, int out_size, void* d_ws, size_t ws_size,
                              hipStream_t stream) {
    const float* x    = (const float*)d_in[0];
    const float* g_w  = (const float*)d_in[1];
    const float* g_b  = (const float*)d_in[2];
    const float* th_w = (const float*)d_in[3];
    const float* th_b = (const float*)d_in[4];
    const float* ph_w = (const float*)d_in[5];
    const float* ph_b = (const float*)d_in[6];
    const float* w_w  = (const float*)d_in[7];
    const float* w_b  = (const float*)d_in[8];
    const float* gam  = (const float*)d_in[9];
    const float* bet  = (const float*)d_in[10];
    const float* mea  = (const float*)d_in[11];
    const float* var  = (const float*)d_in[12];
    float* out = (float*)d_out;
    char* ws = (char*)d_ws;

    __hip_bfloat16* xmt = (__hip_bfloat16*)ws;                    // 64 MiB (written by mix, late)
    __hip_bfloat16* Mw  = (__hip_bfloat16*)(ws + 67108864);       // 2 MiB
    float* xbar  = (float*)(ws + 69206016);                       // 1 MiB
    float* theta = (float*)(ws + 70254592);                       // 512 KiB
    float* phi   = (float*)(ws + 70778880);                       // 512 KiB
    float* attn  = (float*)(ws + 71303168);                       // 8 KiB
    float* inv   = (float*)(ws + 71311360);                       // 4 KiB
    float* shift = (float*)(ws + 71315456);                       // 4 KiB
    // gwt/wwb overlay the xmt region: consumed by stage2 (prepM) BEFORE mix writes xmt
    __hip_bfloat16* gwt = (__hip_bfloat16*)ws;                    // 1 MiB
    __hip_bfloat16* wwb = (__hip_bfloat16*)(ws + 1048576);        // 1 MiB

    hipLaunchKernelGGL(early_kernel, dim3(17184), dim3(256), 0, stream,
                       x, xbar, g_w, w_w, gwt, wwb,
                       g_b, w_b, gam, bet, mea, var, inv, shift);
    hipLaunchKernelGGL(stage2_kernel, dim3(1088), dim3(256), 0, stream,
                       xbar, th_w, th_b, ph_w, ph_b, theta, phi, wwb, gwt, Mw);
    hipLaunchKernelGGL(attn_kernel, dim3(32), dim3(64), 0, stream, theta, phi, attn);
    hipLaunchKernelGGL(mix_kernel, dim3(1024), dim3(256), 0, stream, x, attn, xmt);
    hipLaunchKernelGGL(gemm256x128_kernel, dim3(1024), dim3(512), 0, stream,
                       Mw, xmt, x, inv, shift, out);
}

// Round 15
// 214.496 us; speedup vs baseline: 1.1346x; 1.0153x over previous
//
#include <hip/hip_runtime.h>
#include <hip/hip_bf16.h>

typedef __attribute__((ext_vector_type(8))) short bf16x8;
typedef __attribute__((ext_vector_type(4))) float f32x4;

#if defined(__has_builtin)
#if __has_builtin(__builtin_amdgcn_global_load_lds)
#define USE_GLOAD_LDS 1
#endif
#endif

__device__ __forceinline__ void gload_lds16(const void* g, void* ldsbase) {
#ifdef USE_GLOAD_LDS
    __builtin_amdgcn_global_load_lds(
        (__attribute__((address_space(1))) void*)(g),
        (__attribute__((address_space(3))) void*)(ldsbase), 16, 0, 0);
#endif
}

__device__ __forceinline__ unsigned short f2bf(float f) {
    __hip_bfloat16 h = __float2bfloat16(f);
    return *reinterpret_cast<unsigned short*>(&h);
}

// ============ K1 early: pool (16384) + g_w transpose (512) + w_w cvt (256) + prepbias (32)
__global__ __launch_bounds__(256) void early_kernel(
        const float* __restrict__ x, float* __restrict__ xbar,
        const float* __restrict__ gw, const float* __restrict__ ww,
        __hip_bfloat16* __restrict__ gwt, __hip_bfloat16* __restrict__ wwb,
        const float* __restrict__ gb, const float* __restrict__ wb,
        const float* __restrict__ gamma, const float* __restrict__ beta,
        const float* __restrict__ mean, const float* __restrict__ var,
        float* __restrict__ inv, float* __restrict__ shift) {
    __shared__ float tile[32][33];
    int bid = blockIdx.x;
    int tid = threadIdx.x;
    if (bid < 16384) {
        int row = bid * 16 + (tid >> 4);
        int j = tid & 15;
        const float4* p = (const float4*)(x + (size_t)row * 128);
        float4 a = p[j * 2], b2 = p[j * 2 + 1];
        float s = a.x + a.y + a.z + a.w + b2.x + b2.y + b2.z + b2.w;
        s += __shfl_xor(s, 1); s += __shfl_xor(s, 2);
        s += __shfl_xor(s, 4); s += __shfl_xor(s, 8);
        if (j == 0) xbar[row] = s * (1.0f / 128.0f);
    } else if (bid < 16896) {
        int b2 = bid - 16384;
        int icb = b2 >> 5, cb = b2 & 31;
        int r = tid >> 5, c = tid & 31;
        #pragma unroll
        for (int i = 0; i < 4; i++)
            tile[r + i * 8][c] = gw[(size_t)(icb * 32 + r + i * 8) * 1024 + cb * 32 + c];
        __syncthreads();
        #pragma unroll
        for (int i = 0; i < 4; i++) {
            int cin = cb * 32 + r + i * 8;
            gwt[(size_t)cin * 512 + icb * 32 + c] = __float2bfloat16(tile[c][r + i * 8]);
        }
    } else if (bid < 17152) {
        int b2 = bid - 16896;
        size_t base = (size_t)b2 * 2048 + (size_t)tid * 8;
        const float4* src = (const float4*)(ww + base);
        float4 v0 = src[0], v1 = src[1];
        __hip_bfloat16 tmp[8];
        tmp[0] = __float2bfloat16(v0.x); tmp[1] = __float2bfloat16(v0.y);
        tmp[2] = __float2bfloat16(v0.z); tmp[3] = __float2bfloat16(v0.w);
        tmp[4] = __float2bfloat16(v1.x); tmp[5] = __float2bfloat16(v1.y);
        tmp[6] = __float2bfloat16(v1.z); tmp[7] = __float2bfloat16(v1.w);
        *(bf16x8*)(wwb + base) = *(const bf16x8*)tmp;
    } else {
        int b2 = bid - 17152;
        int wv = tid >> 6, l = tid & 63;
        int c = b2 * 32 + wv * 8 + (l >> 3);
        int j = l & 7;
        const float* wr = ww + (size_t)c * 512;
        float acc = 0.0f;
        #pragma unroll 8
        for (int k = j; k < 512; k += 8) acc += wr[k] * gb[k];
        acc += __shfl_xor(acc, 1); acc += __shfl_xor(acc, 2); acc += __shfl_xor(acc, 4);
        if (j == 0) {
            float cb2 = wb[c] + acc;
            float iv = gamma[c] * rsqrtf(var[c] + 1e-5f);
            inv[c] = iv;
            shift[c] = cb2 * iv + beta[c] - mean[c] * iv;
        }
    }
}

// ============ K2 stage2: thetaphi (1024, LDS-transposed b128 reads) + prepM via MFMA (64)
__global__ __launch_bounds__(256) void stage2_kernel(
        const float* __restrict__ xbar,
        const float* __restrict__ tw, const float* __restrict__ tb,
        const float* __restrict__ pw, const float* __restrict__ pb,
        float* __restrict__ theta, float* __restrict__ phi,
        const __hip_bfloat16* __restrict__ wwb,
        const __hip_bfloat16* __restrict__ gwt,
        __hip_bfloat16* __restrict__ M) {
    __shared__ __align__(16) char smem[33024];
    int bid = blockIdx.x;
    int tid = threadIdx.x;
    if (bid < 1024) {
        float* xs = (float*)smem;
        int which = bid & 1;
        int icc = (bid >> 1) & 15;
        int b = bid >> 5;
        const float* w = which ? pw : tw;
        const float* bias = which ? pb : tb;
        float* out = which ? phi : theta;
        const float* xbb = xbar + b * 8192;
        #pragma unroll
        for (int k = 0; k < 8; ++k) {
            int f4 = tid + k * 256;
            float4 v = *(const float4*)(xbb + (size_t)f4 * 4);
            int c = f4 >> 1;
            int t0 = (f4 & 1) * 4;
            xs[(t0 + 0) * 1028 + c] = v.x;
            xs[(t0 + 1) * 1028 + c] = v.y;
            xs[(t0 + 2) * 1028 + c] = v.z;
            xs[(t0 + 3) * 1028 + c] = v.w;
        }
        __syncthreads();
        int icl = tid >> 3, t = tid & 7;
        int ic = icc * 32 + icl;
        const float* wr = w + (size_t)ic * 1024;
        const float* xr = xs + t * 1028;
        float a0 = 0.0f, a1 = 0.0f;
        #pragma unroll 4
        for (int k = 0; k < 1024; k += 8) {
            float4 wv0 = *(const float4*)(wr + k);
            float4 wv1 = *(const float4*)(wr + k + 4);
            float4 xv0 = *(const float4*)(xr + k);
            float4 xv1 = *(const float4*)(xr + k + 4);
            a0 = fmaf(wv0.x, xv0.x, a0); a0 = fmaf(wv0.y, xv0.y, a0);
            a0 = fmaf(wv0.z, xv0.z, a0); a0 = fmaf(wv0.w, xv0.w, a0);
            a1 = fmaf(wv1.x, xv1.x, a1); a1 = fmaf(wv1.y, xv1.y, a1);
            a1 = fmaf(wv1.z, xv1.z, a1); a1 = fmaf(wv1.w, xv1.w, a1);
        }
        out[((size_t)b * 512 + ic) * 8 + t] = a0 + a1 + bias[ic];
    } else {
        __hip_bfloat16* As = (__hip_bfloat16*)smem;
        __hip_bfloat16* Bs = (__hip_bfloat16*)(smem + 8192);
        int b2 = bid - 1024;
        int mb = b2 >> 3, nb = b2 & 7;
        int c0 = mb * 128, n0 = nb * 128;
        int w = tid >> 6, l = tid & 63;
        int wr = w >> 1, wc = w & 1;
        const __hip_bfloat16* Ab = wwb + (size_t)c0 * 512;
        const __hip_bfloat16* Bb = gwt + (size_t)n0 * 512;
        int arow = tid >> 2, akq = tid & 3;
        f32x4 acc[4][4] = {};
        for (int kk = 0; kk < 16; ++kk) {
            int k0 = kk * 32;
#ifdef USE_GLOAD_LDS
            gload_lds16(Ab + (size_t)arow * 512 + k0 + akq * 8,        (char*)As + w * 1024);
            gload_lds16(Ab + (size_t)(arow + 64) * 512 + k0 + akq * 8, (char*)As + 4096 + w * 1024);
            gload_lds16(Bb + (size_t)arow * 512 + k0 + akq * 8,        (char*)Bs + w * 1024);
            gload_lds16(Bb + (size_t)(arow + 64) * 512 + k0 + akq * 8, (char*)Bs + 4096 + w * 1024);
#else
            *(bf16x8*)((char*)As + (size_t)tid * 16)        = *(const bf16x8*)(Ab + (size_t)arow * 512 + k0 + akq * 8);
            *(bf16x8*)((char*)As + 4096 + (size_t)tid * 16) = *(const bf16x8*)(Ab + (size_t)(arow + 64) * 512 + k0 + akq * 8);
            *(bf16x8*)((char*)Bs + (size_t)tid * 16)        = *(const bf16x8*)(Bb + (size_t)arow * 512 + k0 + akq * 8);
            *(bf16x8*)((char*)Bs + 4096 + (size_t)tid * 16) = *(const bf16x8*)(Bb + (size_t)(arow + 64) * 512 + k0 + akq * 8);
#endif
            __syncthreads();
            const __hip_bfloat16* Ap = As + ((size_t)(wr * 64 + (l & 15)) * 32) + (l >> 4) * 8;
            const __hip_bfloat16* Bp = Bs + ((size_t)(wc * 64 + (l & 15)) * 32) + (l >> 4) * 8;
            bf16x8 af[4], bfr[4];
            #pragma unroll
            for (int m = 0; m < 4; m++) af[m] = *(const bf16x8*)(Ap + m * 16 * 32);
            #pragma unroll
            for (int n = 0; n < 4; n++) bfr[n] = *(const bf16x8*)(Bp + n * 16 * 32);
            #pragma unroll
            for (int m = 0; m < 4; m++)
                #pragma unroll
                for (int n = 0; n < 4; n++)
                    acc[m][n] = __builtin_amdgcn_mfma_f32_16x16x32_bf16(af[m], bfr[n], acc[m][n], 0, 0, 0);
            __syncthreads();
        }
        int col = l & 15, rg = l >> 4;
        #pragma unroll
        for (int m = 0; m < 4; m++)
            #pragma unroll
            for (int j = 0; j < 4; j++) {
                int gc = c0 + wr * 64 + m * 16 + rg * 4 + j;
                #pragma unroll
                for (int n = 0; n < 4; n++)
                    M[(size_t)gc * 1024 + n0 + wc * 64 + n * 16 + col] = __float2bfloat16(acc[m][n][j]);
            }
    }
}

// ===== mix v2 + fused attn: block computes attn[b] in prologue (4-way k-split, redundant
// per block, ~0.5us) then the proven full-row coalesced mix. block = (b, 32-ch), grid 1024.
// xmt[b][t*128+hw][c] = sum_s attn[b][t][s] * x[b][c][s][hw]
__global__ __launch_bounds__(256) void mix_kernel(const float* __restrict__ x,
                                                  const float* __restrict__ theta,
                                                  const float* __restrict__ phi,
                                                  __hip_bfloat16* __restrict__ xmt) {
    int orig = blockIdx.x;
    int wg = (orig & 7) * 128 + (orig >> 3);      // XCD chunk (1024 % 8 == 0)
    int b = wg >> 5;
    int c0 = (wg & 31) * 32;
    __shared__ float at[64];
    __shared__ float fpart[4][64];
    __shared__ __align__(8) unsigned short xls[32 * 1028];
    int tid = threadIdx.x;

    // ---- attn prologue: stage theta/phi[b] into xls region, 4-way k-split dot, softmax ----
    {
        float* thp = (float*)xls;                 // [4096]
        float* php = (float*)xls + 4096;          // [4096]
        const float4* thg = (const float4*)(theta + (size_t)b * 4096);
        const float4* phg = (const float4*)(phi + (size_t)b * 4096);
        float4* thp4 = (float4*)thp;
        float4* php4 = (float4*)php;
        #pragma unroll
        for (int k = 0; k < 4; ++k) {
            int i = tid + k * 256;                // 0..1023
            thp4[i] = thg[i];
            php4[i] = phg[i];
        }
        __syncthreads();
        int p = tid & 63, ks = tid >> 6;
        int t = p >> 3, s = p & 7;
        const float* thr = thp + ks * 1024;       // ics ks*128..+128, layout [ic*8+t]
        const float* phr = php + ks * 1024;
        float f = 0.0f;
        #pragma unroll 8
        for (int ic = 0; ic < 128; ++ic) f = fmaf(thr[ic * 8 + t], phr[ic * 8 + s], f);
        fpart[ks][p] = f;
        __syncthreads();
        if (tid < 64) {
            float ftot = fpart[0][tid] + fpart[1][tid] + fpart[2][tid] + fpart[3][tid];
            float m = ftot;
            m = fmaxf(m, __shfl_xor(m, 1));
            m = fmaxf(m, __shfl_xor(m, 2));
            m = fmaxf(m, __shfl_xor(m, 4));
            float e = __expf(ftot - m);
            float sum = e;
            sum += __shfl_xor(sum, 1); sum += __shfl_xor(sum, 2); sum += __shfl_xor(sum, 4);
            at[tid] = e / sum;
        }
        __syncthreads();                          // at ready; xls free to overwrite
    }

    // ---- mix body (R10-proven) ----
    const float* xb = x + ((size_t)b << 20) + (size_t)c0 * 1024;
    #pragma unroll
    for (int k = 0; k < 32; ++k) {
        int f4 = tid + k * 256;                   // 0..8191
        float4 v = *(const float4*)(xb + (size_t)f4 * 4);
        int ci = f4 >> 8;
        int rem = (f4 & 255) * 4;
        unsigned short h[4];
        h[0] = f2bf(v.x); h[1] = f2bf(v.y); h[2] = f2bf(v.z); h[3] = f2bf(v.w);
        *(ushort4*)(&xls[ci * 1028 + rem]) = *(const ushort4*)h;
    }
    __syncthreads();
    int ci = tid & 31, h2 = tid >> 5;
    const unsigned short* basep = &xls[ci * 1028];
    __hip_bfloat16* ob = xmt + ((size_t)b << 20) + c0 + ci;
    #pragma unroll
    for (int i = 0; i < 8; ++i) {
        int hw0 = (h2 + 8 * i) * 2;
        float o0[8] = {}, o1[8] = {};
        #pragma unroll
        for (int s = 0; s < 8; ++s) {
            unsigned int pr = *(const unsigned int*)(basep + s * 128 + hw0);
            float v0 = __uint_as_float(pr << 16);
            float v1 = __uint_as_float(pr & 0xffff0000u);
            #pragma unroll
            for (int t = 0; t < 8; ++t) {
                float a = at[t * 8 + s];
                o0[t] = fmaf(a, v0, o0[t]);
                o1[t] = fmaf(a, v1, o1[t]);
            }
        }
        #pragma unroll
        for (int t = 0; t < 8; ++t) {
            size_t nn = (size_t)(t * 128 + hw0) * 1024;
            ob[nn] = __float2bfloat16(o0[t]);
            ob[nn + 1024] = __float2bfloat16(o1[t]);
        }
    }
}

// ===== 256x128-tile / 8-wave GEMM, K32 dbuf + counted vmcnt(3), 2 blocks/CU (48 KB LDS) =====
// out[b][c][n] = inv[c] * sum_k M[c][k]*xmt[b][n][k] + shift[c] + x[b][c][n]
// NOTE: 2 blocks/CU is the register ceiling for this tile (64 acc + 64 VGPR = 128 = cap at
// 4 waves/SIMD); 3 blocks/CU would need <=85 regs -> spill (R6 lesson). Do not raise.
__global__ __launch_bounds__(512, 4) void gemm256x128_kernel(
        const __hip_bfloat16* __restrict__ Mw,    // [1024][1024]  (c, k)
        const __hip_bfloat16* __restrict__ xmt,   // [32][1024][1024] (n, k)
        const float* __restrict__ x,              // [32][1024][1024] (c, n)
        const float* __restrict__ inv, const float* __restrict__ shift,
        float* __restrict__ out) {
    __shared__ __align__(16) __hip_bfloat16 HBs[24576];        // 48 KiB = 2 x 24 KiB
    char* AH = (char*)HBs;
    const int BUFB = 24576;

    int orig = blockIdx.x;
    int bid = (orig & 7) * 128 + (orig >> 3);     // XCD chunk (1024 % 8 == 0)
    int b = bid >> 5;
    int mb = (bid >> 3) & 3;
    int nb = bid & 7;
    int c0 = mb * 256, n0 = nb * 128;

    int tid = threadIdx.x;
    int w = tid >> 6, l = tid & 63;
    int wr = w >> 1, wc = w & 1;                  // 4x2 waves; wave out = 64(M) x 64(N)

    int sgl = (((l & 3) - ((l >> 3) & 3)) & 3);
    const __hip_bfloat16* aS = Mw + (size_t)(c0 + w * 16 + (l >> 2)) * 1024 + sgl * 8;
    const __hip_bfloat16* bS = xmt + ((size_t)b << 20) + (size_t)(n0 + w * 16 + (l >> 2)) * 1024 + sgl * 8;
    int stBase = w * 1024;

    int rdSlot = ((l >> 4) + (((l & 15) >> 1) & 3)) & 3;
    int aRdBase = (wr * 64 + (l & 15)) * 64 + rdSlot * 16;          // A region: 16 KB
    int bRdBase = 16384 + (wc * 64 + (l & 15)) * 64 + rdSlot * 16;  // B region: 8 KB

    f32x4 acc[4][4] = {};

    #define ISSUE(q) do {                                                       \
        gload_lds16(aS,              AH + (q) * BUFB + stBase);                 \
        gload_lds16(aS + 128 * 1024, AH + (q) * BUFB + 8192 + stBase);          \
        gload_lds16(bS,              AH + (q) * BUFB + 16384 + stBase);         \
        aS += 32; bS += 32;                                                     \
    } while (0)

    #define V3 asm volatile("s_waitcnt vmcnt(3)" ::: "memory")
    #define V0 asm volatile("s_waitcnt vmcnt(0)" ::: "memory")
    #define SB0 __builtin_amdgcn_sched_barrier(0)
    #define BAR __builtin_amdgcn_s_barrier()
    #define LGKM0 asm volatile("s_waitcnt lgkmcnt(0)" ::: "memory")

    #define HSTEP(q, MODE) do {                                                 \
        const char* bp = AH + (q) * BUFB;                                       \
        bf16x8 af0 = *(const bf16x8*)(bp + aRdBase);                            \
        bf16x8 af1 = *(const bf16x8*)(bp + aRdBase + 1024);                     \
        bf16x8 af2 = *(const bf16x8*)(bp + aRdBase + 2048);                     \
        bf16x8 af3 = *(const bf16x8*)(bp + aRdBase + 3072);                     \
        bf16x8 bf0 = *(const bf16x8*)(bp + bRdBase);                            \
        bf16x8 bf1 = *(const bf16x8*)(bp + bRdBase + 1024);                     \
        bf16x8 bf2 = *(const bf16x8*)(bp + bRdBase + 2048);                     \
        bf16x8 bf3 = *(const bf16x8*)(bp + bRdBase + 3072);                     \
        LGKM0; SB0;                                                             \
        BAR;                                                                    \
        if ((MODE) == 0) ISSUE(q);                                              \
        SB0;                                                                    \
        __builtin_amdgcn_s_setprio(1);                                          \
        _Pragma("unroll")                                                       \
        for (int n = 0; n < 4; ++n) {                                           \
            bf16x8 bfn = (n == 0) ? bf0 : (n == 1) ? bf1 : (n == 2) ? bf2 : bf3;\
            acc[0][n] = __builtin_amdgcn_mfma_f32_16x16x32_bf16(af0, bfn, acc[0][n], 0, 0, 0); \
            acc[1][n] = __builtin_amdgcn_mfma_f32_16x16x32_bf16(af1, bfn, acc[1][n], 0, 0, 0); \
            acc[2][n] = __builtin_amdgcn_mfma_f32_16x16x32_bf16(af2, bfn, acc[2][n], 0, 0, 0); \
            acc[3][n] = __builtin_amdgcn_mfma_f32_16x16x32_bf16(af3, bfn, acc[3][n], 0, 0, 0); \
        }                                                                       \
        __builtin_amdgcn_s_setprio(0);                                          \
        SB0;                                                                    \
        if ((MODE) == 0) { V3; BAR; SB0; }                                      \
        else if ((MODE) == 1) { V0; BAR; SB0; }                                 \
    } while (0)

    ISSUE(0); ISSUE(1);
    V3; BAR; SB0;

    #pragma unroll 1
    for (int t = 0; t < 15; ++t) {
        HSTEP(0, 0);
        HSTEP(1, 0);
    }
    HSTEP(0, 1);
    HSTEP(1, 2);

    #undef ISSUE
    #undef HSTEP
    #undef V3
    #undef V0
    #undef SB0
    #undef BAR
    #undef LGKM0

    int col = l & 15, rg = l >> 4;
    const float* xb = x + ((size_t)b << 20);
    float* ob = out + ((size_t)b << 20);
    #pragma unroll
    for (int mi = 0; mi < 4; ++mi) {
        #pragma unroll
        for (int j = 0; j < 4; ++j) {
            int gc = c0 + wr * 64 + mi * 16 + rg * 4 + j;
            float iv = inv[gc], sh = shift[gc];
            size_t rowoff = (size_t)gc * 1024 + n0 + wc * 64 + col;
            #pragma unroll
            for (int n = 0; n < 4; ++n) {
                size_t idx = rowoff + n * 16;
                ob[idx] = acc[mi][n][j] * iv + sh + xb[idx];
            }
        }
    }
}

extern "C" void kernel_launch(void* const* d_in, const int* in_sizes, int n_in,
                              void* d_out, int out_size, void* d_ws, size_t ws_size,
                              hipStream_t stream) {
    const float* x    = (const float*)d_in[0];
    const float* g_w  = (const float*)d_in[1];
    const float* g_b  = (const float*)d_in[2];
    const float* th_w = (const float*)d_in[3];
    const float* th_b = (const float*)d_in[4];
    const float* ph_w = (const float*)d_in[5];
    const float* ph_b = (const float*)d_in[6];
    const float* w_w  = (const float*)d_in[7];
    const float* w_b  = (const float*)d_in[8];
    const float* gam  = (const float*)d_in[9];
    const float* bet  = (const float*)d_in[10];
    const float* mea  = (const float*)d_in[11];
    const float* var  = (const float*)d_in[12];
    float* out = (float*)d_out;
    char* ws = (char*)d_ws;

    __hip_bfloat16* xmt = (__hip_bfloat16*)ws;                    // 64 MiB (written by mix, late)
    __hip_bfloat16* Mw  = (__hip_bfloat16*)(ws + 67108864);       // 2 MiB
    float* xbar  = (float*)(ws + 69206016);                       // 1 MiB
    float* theta = (float*)(ws + 70254592);                       // 512 KiB
    float* phi   = (float*)(ws + 70778880);                       // 512 KiB
    float* inv   = (float*)(ws + 71311360);                       // 4 KiB
    float* shift = (float*)(ws + 71315456);                       // 4 KiB
    // gwt/wwb overlay the xmt region: consumed by stage2 (prepM) BEFORE mix writes xmt
    __hip_bfloat16* gwt = (__hip_bfloat16*)ws;                    // 1 MiB
    __hip_bfloat16* wwb = (__hip_bfloat16*)(ws + 1048576);        // 1 MiB

    hipLaunchKernelGGL(early_kernel, dim3(17184), dim3(256), 0, stream,
                       x, xbar, g_w, w_w, gwt, wwb,
                       g_b, w_b, gam, bet, mea, var, inv, shift);
    hipLaunchKernelGGL(stage2_kernel, dim3(1088), dim3(256), 0, stream,
                       xbar, th_w, th_b, ph_w, ph_b, theta, phi, wwb, gwt, Mw);
    hipLaunchKernelGGL(mix_kernel, dim3(1024), dim3(256), 0, stream,
                       x, theta, phi, xmt);
    hipLaunchKernelGGL(gemm256x128_kernel, dim3(1024), dim3(512), 0, stream,
                       Mw, xmt, x, inv, shift, out);
}